// Round 11
// baseline (167.186 us; speedup 1.0000x reference)
//
#include <hip/hip_runtime.h>
#include <math.h>

// Problem constants
#define NS 64    // sentences
#define NW 64    // words per sentence
#define NE 300   // embedding dim
#define NH 50    // hidden
#define NO 5     // output classes
#define SPIN_TICKS 150000ULL   // ~75 us @ 2.0 GHz SCLK (R5-measured)

// Session facts (measured):
//  - R5: SCLK ~2.0 GHz near-idle; clock64 ticks at SCLK.
//  - R1..R6: weight-array spill was the ~1us/step invariant; R8 f16-packed
//    weights fixed it (78 -> 48 us). R10 depth-4 X prefetch: 48 -> 42.7 us.
//  - R9: bulk-LDS staging + 2-block scan + memset REGRESSED. Avoid.
//  - R11 (this round): DIAGNOSTIC. Tail-spins (~75us) in both kernels lift
//    them into rocprof top-5 -> per-kernel true durations + k_scan VGPR.
//    Real fix included: weights pre-packed lane-order by a 65th k_reps block
//    -> k_scan prologue is 75 coalesced dword loads instead of 450 strided.

typedef __fp16 half2v __attribute__((ext_vector_type(2)));

__device__ __forceinline__ float fdot2(half2v a, half2v b, float c) {
  return __builtin_amdgcn_fdot2(a, b, c, false);   // v_dot2_f32_f16
}
__device__ __forceinline__ float fast_tanh(float x) {
  x = fminf(15.f, fmaxf(-15.f, x));
  const float e = __expf(2.f * x);
  return 1.f - 2.f * __builtin_amdgcn_rcpf(e + 1.f);
}
__device__ __forceinline__ float fast_sigmoid(float x) {
  return __builtin_amdgcn_rcpf(1.f + __expf(-x));
}
__device__ __forceinline__ void tail_spin() {
  const unsigned long long t0 = clock64();
  while (clock64() - t0 < SPIN_TICKS) {}
}

// d_ws layout (floats):
//   [64 .. 64+19200)          Xg  (2*64*3*50)
//   [64+19200 .. +7500 u32)   pw  (packed f16x2 weights, lane-order)

// ---------------------------------------------------------------------------
// K1: per-sentence reps + x-part preactivations; block 64 packs the weights.
// ---------------------------------------------------------------------------
__global__ __launch_bounds__(512) void k_reps(
    const int* __restrict__ doc, const float* __restrict__ emb,
    const float* __restrict__ Wword, const float* __restrict__ bword,
    const float* __restrict__ w1, const float* __restrict__ b1,
    const float* __restrict__ w2, const float* __restrict__ b2,
    const float* __restrict__ w3, const float* __restrict__ b3,
    const float* __restrict__ Wfi, const float* __restrict__ bfi,
    const float* __restrict__ Wff, const float* __restrict__ bff,
    const float* __restrict__ Wfg, const float* __restrict__ bfg,
    const float* __restrict__ Wbi, const float* __restrict__ bbi,
    const float* __restrict__ Wbf, const float* __restrict__ bbf,
    const float* __restrict__ Wbg, const float* __restrict__ bbg,
    float* __restrict__ Xg, unsigned int* __restrict__ pw)
{
  __shared__ int   idxs[NW];
  __shared__ float sv[5][304];    // 0: word-sum; 1..4: rows 0,1,62,63
  __shared__ float ph1[304];      // group-1 partial of the w-sum
  __shared__ float dots[5][NH];
  __shared__ float reps_s[NH];

  const int s = blockIdx.x, tid = threadIdx.x;

  if (s == NS) {
    // ---- weight-packing block: pw[((d*3+gate)*25+c)*50+j] = f16x2 pair ----
    for (int idx = tid; idx < 7500; idx += 512) {
      const int j  = idx % 50;
      const int c  = (idx / 50) % 25;
      const int dg = idx / 1250;          // (d*3+gate), 0..5
      const float* Wp;
      switch (dg) {
        case 0: Wp = Wfi; break;
        case 1: Wp = Wff; break;
        case 2: Wp = Wfg; break;
        case 3: Wp = Wbi; break;
        case 4: Wp = Wbf; break;
        default: Wp = Wbg; break;
      }
      const int base = j * 100 + 50 + 2 * c;
      const half2v v = __builtin_amdgcn_cvt_pkrtz(Wp[base], Wp[base + 1]);
      pw[idx] = __builtin_bit_cast(unsigned int, v);
    }
    tail_spin();
    return;
  }

  if (tid < NW) idxs[tid] = doc[s * NW + tid];
  __syncthreads();

  // Phase B: column sums of the 64 gathered rows, 2 groups x 32-deep.
  const int p = tid >> 8, et = tid & 255;
  for (int e = et; e < NE; e += 256) {
    float acc = 0.f;
    const int w0 = p * 32;
#pragma unroll 8
    for (int w = w0; w < w0 + 32; ++w)
      acc += emb[(size_t)idxs[w] * NE + e];
    if (p == 0) sv[0][e] = acc; else ph1[e] = acc;
    if (p == 0) {
      sv[1][e] = emb[(size_t)idxs[0]  * NE + e];
      sv[2][e] = emb[(size_t)idxs[1]  * NE + e];
    } else {
      sv[3][e] = emb[(size_t)idxs[62] * NE + e];
      sv[4][e] = emb[(size_t)idxs[63] * NE + e];
    }
  }
  __syncthreads();
  if (tid < NE) sv[0][tid] += ph1[tid];
  __syncthreads();

  // Phase C: 5 families x 50 outputs, 300-dots against W_word rows.
  if (tid < 5 * NH) {
    const int fam = tid / NH, i = tid % NH;
    const float4* v4 = (const float4*)&sv[fam][0];
    const float4* w4 = (const float4*)(Wword + (size_t)i * NE);
    float a0 = 0.f, a1 = 0.f;
#pragma unroll
    for (int c = 0; c < NE / 4; ++c) {
      const float4 v = v4[c], w = w4[c];
      a0 += v.x * w.x + v.y * w.y;
      a1 += v.z * w.z + v.w * w.w;
    }
    dots[fam][i] = a0 + a1;
  }
  __syncthreads();

  // Phase D: conv means + tanh + average -> reps_s
  if (tid < NH) {
    const int o = tid;
    float m1 = 0.f, m2 = 0.f, m3 = 0.f;
    for (int i = 0; i < NH; ++i) {
      const float bw    = bword[i];
      const float total = dots[0][i] + 64.f * bw;
      const float e0  = dots[1][i] + bw;
      const float e1  = dots[2][i] + bw;
      const float e62 = dots[3][i] + bw;
      const float e63 = dots[4][i] + bw;
      m1 += w1[o * NH + i] * total;
      m2 += w2[(o * NH + i) * 2 + 0] * (total - e63)
          + w2[(o * NH + i) * 2 + 1] * (total - e0);
      m3 += w3[(o * NH + i) * 3 + 0] * (total - e62 - e63)
          + w3[(o * NH + i) * 3 + 1] * (total - e0 - e63)
          + w3[(o * NH + i) * 3 + 2] * (total - e0 - e1);
    }
    m1 = b1[o] + m1 * (1.f / 64.f);
    m2 = b2[o] + m2 * (1.f / 63.f);
    m3 = b3[o] + m3 * (1.f / 62.f);
    reps_s[o] = (fast_tanh(m1) + fast_tanh(m2) + fast_tanh(m3)) * (1.f / 3.f);
  }
  __syncthreads();

  // Phase E: x-part gate preactivations for both directions.
  if (tid < 6 * NH) {
    const int dg = tid / NH, j = tid % NH;
    const float* Wp; const float* bp;
    switch (dg) {
      case 0: Wp = Wfi; bp = bfi; break;
      case 1: Wp = Wff; bp = bff; break;
      case 2: Wp = Wfg; bp = bfg; break;
      case 3: Wp = Wbi; bp = bbi; break;
      case 4: Wp = Wbf; bp = bbf; break;
      default: Wp = Wbg; bp = bbg; break;
    }
    float acc = bp[j];
    for (int k = 0; k < NH; ++k) acc += Wp[j * 100 + k] * reps_s[k];
    const int dir = dg / 3, gate = dg % 3;
    Xg[((dir * NS + s) * 3 + gate) * NH + j] = acc;
  }
  tail_spin();
}

// ---------------------------------------------------------------------------
// K2 (R10 structure): 1 block x 2 waves (wave = direction), f16-packed
// weights in registers, zero barriers in the loop, depth-4 X prefetch,
// in-block epilogue. Change vs R10: prologue reads pre-packed pw
// (75 coalesced dwords/lane) instead of 450 strided scalar loads.
// ---------------------------------------------------------------------------
struct X3 { float i, f, g; };

__global__ __launch_bounds__(128, 1) void k_scan(
    const float* __restrict__ Xg, const unsigned int* __restrict__ pw,
    const float* __restrict__ Wout, const float* __restrict__ bout,
    float* __restrict__ out)
{
  __shared__ float gsum_sh[2 * NH];

  const int tid = threadIdx.x;
  const int d   = tid >> 6;                 // wave = direction
  const int lane = tid & 63;
  const int j   = (lane < NH) ? lane : 0;   // lanes 50..63 shadow lane 0

  // coalesced prologue: 75 dword loads/lane from lane-order packed weights
  half2v wi2[25], wf2[25], wg2[25];
#pragma unroll
  for (int c = 0; c < 25; ++c) {
    wi2[c] = __builtin_bit_cast(half2v, pw[((d * 3 + 0) * 25 + c) * 50 + j]);
    wf2[c] = __builtin_bit_cast(half2v, pw[((d * 3 + 1) * 25 + c) * 50 + j]);
    wg2[c] = __builtin_bit_cast(half2v, pw[((d * 3 + 2) * 25 + c) * 50 + j]);
  }

  const float* Xd = Xg + d * NS * 3 * NH;

  auto ldx = [&](int t) -> X3 {
    const int tt = d ? (NS - 1 - t) : t;
    X3 r;
    r.i = Xd[tt * 150 + j];
    r.f = Xd[tt * 150 + 50 + j];
    r.g = Xd[tt * 150 + 100 + j];
    return r;
  };

  float hj = 0.f, hs = 0.f;

  auto dostep = [&](X3 x) {
    float ai0 = x.i, af0 = x.f, ag0 = x.g;
    float ai1 = 0.f, af1 = 0.f, ag1 = 0.f;
    const float hpart = __builtin_bit_cast(float,
        __builtin_amdgcn_ds_swizzle(__builtin_bit_cast(int, hj), 0x041F));
    const half2v hpk = __builtin_amdgcn_cvt_pkrtz(hj, hpart);
    const int packed = __builtin_bit_cast(int, hpk);
#pragma unroll
    for (int c = 0; c < 25; ++c) {
      const half2v hk2 = __builtin_bit_cast(half2v,
          __builtin_amdgcn_readlane(packed, 2 * c));
      if (c & 1) {
        ai1 = fdot2(wi2[c], hk2, ai1);
        af1 = fdot2(wf2[c], hk2, af1);
        ag1 = fdot2(wg2[c], hk2, ag1);
      } else {
        ai0 = fdot2(wi2[c], hk2, ai0);
        af0 = fdot2(wf2[c], hk2, af0);
        ag0 = fdot2(wg2[c], hk2, ag0);
      }
    }
    const float it = fast_sigmoid(ai0 + ai1);
    const float ft = fast_sigmoid(af0 + af1);
    const float gt = fast_tanh(ag0 + ag1);
    hj = fast_tanh(it * gt + ft * hj);
    hs += hj;
  };

  // Depth-4 rolling prefetch: named slots, statically indexed.
  X3 p0 = ldx(0), p1 = ldx(1), p2 = ldx(2), p3 = ldx(3);

#pragma unroll 1
  for (int k = 0; k < NS / 4; ++k) {
    const int n = 4 * k;
    const int q0 = (n + 4 < NS) ? n + 4 : NS - 1;
    const int q1 = (n + 5 < NS) ? n + 5 : NS - 1;
    const int q2 = (n + 6 < NS) ? n + 6 : NS - 1;
    const int q3 = (n + 7 < NS) ? n + 7 : NS - 1;
    X3 c0 = p0; p0 = ldx(q0); dostep(c0);
    X3 c1 = p1; p1 = ldx(q1); dostep(c1);
    X3 c2 = p2; p2 = ldx(q2); dostep(c2);
    X3 c3 = p3; p3 = ldx(q3); dostep(c3);
  }

  if (lane < NH) gsum_sh[d * NH + lane] = hs * (1.f / 64.f);
  __syncthreads();

  // Epilogue (wave 0): logits + softmax
  if (d == 0) {
    float lg = 0.f;
    if (lane < NO) {
      float acc = bout[lane];
      for (int k = 0; k < 2 * NH; ++k) acc += Wout[lane * 2 * NH + k] * gsum_sh[k];
      lg = acc;
    }
    const float l0 = __shfl(lg, 0), l1 = __shfl(lg, 1), l2 = __shfl(lg, 2),
                l3 = __shfl(lg, 3), l4 = __shfl(lg, 4);
    if (lane == 0) {
      const float m = fmaxf(fmaxf(fmaxf(l0, l1), fmaxf(l2, l3)), l4);
      const float e0 = __expf(l0 - m), e1 = __expf(l1 - m), e2 = __expf(l2 - m),
                  e3 = __expf(l3 - m), e4 = __expf(l4 - m);
      const float se = e0 + e1 + e2 + e3 + e4;
      out[0] = e0 / se; out[1] = e1 / se; out[2] = e2 / se;
      out[3] = e3 / se; out[4] = e4 / se;
    }
  }
  tail_spin();
}

extern "C" void kernel_launch(void* const* d_in, const int* in_sizes, int n_in,
                              void* d_out, int out_size, void* d_ws, size_t ws_size,
                              hipStream_t stream) {
  const int*   doc   = (const int*)  d_in[0];
  const float* emb   = (const float*)d_in[1];
  const float* Wword = (const float*)d_in[2];
  const float* bword = (const float*)d_in[3];
  const float* w1    = (const float*)d_in[4];
  const float* b1    = (const float*)d_in[5];
  const float* w2    = (const float*)d_in[6];
  const float* b2    = (const float*)d_in[7];
  const float* w3    = (const float*)d_in[8];
  const float* b3    = (const float*)d_in[9];
  const float* Wfi   = (const float*)d_in[10];
  const float* bfi   = (const float*)d_in[11];
  const float* Wff   = (const float*)d_in[12];
  const float* bff   = (const float*)d_in[13];
  const float* Wfg   = (const float*)d_in[14];
  const float* bfg   = (const float*)d_in[15];
  const float* Wbi   = (const float*)d_in[16];
  const float* bbi   = (const float*)d_in[17];
  const float* Wbf   = (const float*)d_in[18];
  const float* bbf   = (const float*)d_in[19];
  const float* Wbg   = (const float*)d_in[20];
  const float* bbg   = (const float*)d_in[21];
  const float* Wout  = (const float*)d_in[22];
  const float* bout  = (const float*)d_in[23];

  float* Xg = (float*)d_ws + 64;                         // 19200 floats
  unsigned int* pw = (unsigned int*)((float*)d_ws + 64 + 19200);  // 7500 u32

  k_reps<<<dim3(NS + 1), dim3(512), 0, stream>>>(
      doc, emb, Wword, bword, w1, b1, w2, b2, w3, b3,
      Wfi, bfi, Wff, bff, Wfg, bfg, Wbi, bbi, Wbf, bbf, Wbg, bbg,
      Xg, pw);

  k_scan<<<dim3(1), dim3(128), 0, stream>>>(
      Xg, pw, Wout, bout, (float*)d_out);
}

// Round 12
// 37.928 us; speedup vs baseline: 4.4080x; 4.4080x over previous
//
#include <hip/hip_runtime.h>
#include <math.h>

// Problem constants
#define NS 64    // sentences
#define NW 64    // words per sentence
#define NE 300   // embedding dim
#define NH 50    // hidden
#define NO 5     // output classes

// Session facts (measured):
//  - R5: SCLK ~2.0 GHz near-idle; clock64 ticks ~SCLK.
//  - R8: f16-packed scan weights (75 VGPR) killed the spill invariant.
//  - R11 spin-diagnostic: k_reps true ~18.6us (dominant), k_scan true ~0-3us
//    AFTER the pw-coalesced prologue (R10's k_scan prologue was ~20us:
//    450 strided scalar loads/lane over L3-cold weight matrices).
//  - R12: spins removed; k_reps Phase D parallelized 50->400 threads
//    (8-way i-split + shfl_xor octet reduce); Phase B unroll 16.

typedef __fp16 half2v __attribute__((ext_vector_type(2)));

__device__ __forceinline__ float fdot2(half2v a, half2v b, float c) {
  return __builtin_amdgcn_fdot2(a, b, c, false);   // v_dot2_f32_f16
}
__device__ __forceinline__ float fast_tanh(float x) {
  x = fminf(15.f, fmaxf(-15.f, x));
  const float e = __expf(2.f * x);
  return 1.f - 2.f * __builtin_amdgcn_rcpf(e + 1.f);
}
__device__ __forceinline__ float fast_sigmoid(float x) {
  return __builtin_amdgcn_rcpf(1.f + __expf(-x));
}

// d_ws layout:
//   [64 .. 64+19200) floats    Xg  (2*64*3*50)
//   then 7500 u32              pw  (packed f16x2 weights, lane-order)

// ---------------------------------------------------------------------------
// K1: per-sentence reps + x-part preactivations; block 64 packs the weights.
// ---------------------------------------------------------------------------
__global__ __launch_bounds__(512) void k_reps(
    const int* __restrict__ doc, const float* __restrict__ emb,
    const float* __restrict__ Wword, const float* __restrict__ bword,
    const float* __restrict__ w1, const float* __restrict__ b1,
    const float* __restrict__ w2, const float* __restrict__ b2,
    const float* __restrict__ w3, const float* __restrict__ b3,
    const float* __restrict__ Wfi, const float* __restrict__ bfi,
    const float* __restrict__ Wff, const float* __restrict__ bff,
    const float* __restrict__ Wfg, const float* __restrict__ bfg,
    const float* __restrict__ Wbi, const float* __restrict__ bbi,
    const float* __restrict__ Wbf, const float* __restrict__ bbf,
    const float* __restrict__ Wbg, const float* __restrict__ bbg,
    float* __restrict__ Xg, unsigned int* __restrict__ pw)
{
  __shared__ int   idxs[NW];
  __shared__ float sv[5][304];    // 0: word-sum; 1..4: rows 0,1,62,63
  __shared__ float ph1[304];      // group-1 partial of the w-sum
  __shared__ float dots[5][NH];
  __shared__ float reps_s[NH];

  const int s = blockIdx.x, tid = threadIdx.x;

  if (s == NS) {
    // ---- weight-packing block: pw[((d*3+gate)*25+c)*50+j] = f16x2 pair ----
    for (int idx = tid; idx < 7500; idx += 512) {
      const int j  = idx % 50;
      const int c  = (idx / 50) % 25;
      const int dg = idx / 1250;          // (d*3+gate), 0..5
      const float* Wp;
      switch (dg) {
        case 0: Wp = Wfi; break;
        case 1: Wp = Wff; break;
        case 2: Wp = Wfg; break;
        case 3: Wp = Wbi; break;
        case 4: Wp = Wbf; break;
        default: Wp = Wbg; break;
      }
      const int base = j * 100 + 50 + 2 * c;
      const half2v v = __builtin_amdgcn_cvt_pkrtz(Wp[base], Wp[base + 1]);
      pw[idx] = __builtin_bit_cast(unsigned int, v);
    }
    return;
  }

  if (tid < NW) idxs[tid] = doc[s * NW + tid];
  __syncthreads();

  // Phase B: column sums of the 64 gathered rows, 2 groups x 32-deep.
  // unroll 16 -> 16 gather loads in flight (hides ~900cy L3/HBM latency).
  const int p = tid >> 8, et = tid & 255;
  for (int e = et; e < NE; e += 256) {
    float acc = 0.f;
    const int w0 = p * 32;
#pragma unroll 16
    for (int w = w0; w < w0 + 32; ++w)
      acc += emb[(size_t)idxs[w] * NE + e];
    if (p == 0) sv[0][e] = acc; else ph1[e] = acc;
    if (p == 0) {
      sv[1][e] = emb[(size_t)idxs[0]  * NE + e];
      sv[2][e] = emb[(size_t)idxs[1]  * NE + e];
    } else {
      sv[3][e] = emb[(size_t)idxs[62] * NE + e];
      sv[4][e] = emb[(size_t)idxs[63] * NE + e];
    }
  }
  __syncthreads();
  if (tid < NE) sv[0][tid] += ph1[tid];
  __syncthreads();

  // Phase C: 5 families x 50 outputs, 300-dots against W_word rows.
  if (tid < 5 * NH) {
    const int fam = tid / NH, i = tid % NH;
    const float4* v4 = (const float4*)&sv[fam][0];
    const float4* w4 = (const float4*)(Wword + (size_t)i * NE);
    float a0 = 0.f, a1 = 0.f;
#pragma unroll
    for (int c = 0; c < NE / 4; ++c) {
      const float4 v = v4[c], w = w4[c];
      a0 += v.x * w.x + v.y * w.y;
      a1 += v.z * w.z + v.w * w.w;
    }
    dots[fam][i] = a0 + a1;
  }
  __syncthreads();

  // Phase D: conv means + tanh + average -> reps_s.
  // 400 threads: o = tid/8, part = tid&7; 8-way i-split, coalesced 32-96B
  // segments per octet, then 3-level shfl_xor reduce within the octet.
  if (tid < 8 * NH) {
    const int o = tid >> 3, part = tid & 7;
    float m1 = 0.f, m2 = 0.f, m3 = 0.f;
    for (int i = part; i < NH; i += 8) {
      const float bw    = bword[i];
      const float total = dots[0][i] + 64.f * bw;
      const float e0  = dots[1][i] + bw;
      const float e1  = dots[2][i] + bw;
      const float e62 = dots[3][i] + bw;
      const float e63 = dots[4][i] + bw;
      m1 += w1[o * NH + i] * total;
      m2 += w2[(o * NH + i) * 2 + 0] * (total - e63)
          + w2[(o * NH + i) * 2 + 1] * (total - e0);
      m3 += w3[(o * NH + i) * 3 + 0] * (total - e62 - e63)
          + w3[(o * NH + i) * 3 + 1] * (total - e0 - e63)
          + w3[(o * NH + i) * 3 + 2] * (total - e0 - e1);
    }
#pragma unroll
    for (int m = 1; m < 8; m <<= 1) {
      m1 += __shfl_xor(m1, m);
      m2 += __shfl_xor(m2, m);
      m3 += __shfl_xor(m3, m);
    }
    if (part == 0) {
      m1 = b1[o] + m1 * (1.f / 64.f);
      m2 = b2[o] + m2 * (1.f / 63.f);
      m3 = b3[o] + m3 * (1.f / 62.f);
      reps_s[o] = (fast_tanh(m1) + fast_tanh(m2) + fast_tanh(m3)) * (1.f / 3.f);
    }
  }
  __syncthreads();

  // Phase E: x-part gate preactivations for both directions.
  if (tid < 6 * NH) {
    const int dg = tid / NH, j = tid % NH;
    const float* Wp; const float* bp;
    switch (dg) {
      case 0: Wp = Wfi; bp = bfi; break;
      case 1: Wp = Wff; bp = bff; break;
      case 2: Wp = Wfg; bp = bfg; break;
      case 3: Wp = Wbi; bp = bbi; break;
      case 4: Wp = Wbf; bp = bbf; break;
      default: Wp = Wbg; bp = bbg; break;
    }
    float acc = bp[j];
    for (int k = 0; k < NH; ++k) acc += Wp[j * 100 + k] * reps_s[k];
    const int dir = dg / 3, gate = dg % 3;
    Xg[((dir * NS + s) * 3 + gate) * NH + j] = acc;
  }
}

// ---------------------------------------------------------------------------
// K2 (R11 structure, spin removed): 1 block x 2 waves (wave = direction),
// coalesced pw prologue, f16 weights in registers, zero in-loop barriers,
// depth-4 X prefetch, in-block epilogue.
// ---------------------------------------------------------------------------
struct X3 { float i, f, g; };

__global__ __launch_bounds__(128, 1) void k_scan(
    const float* __restrict__ Xg, const unsigned int* __restrict__ pw,
    const float* __restrict__ Wout, const float* __restrict__ bout,
    float* __restrict__ out)
{
  __shared__ float gsum_sh[2 * NH];

  const int tid = threadIdx.x;
  const int d   = tid >> 6;                 // wave = direction
  const int lane = tid & 63;
  const int j   = (lane < NH) ? lane : 0;   // lanes 50..63 shadow lane 0

  // coalesced prologue: 75 dword loads/lane from lane-order packed weights
  half2v wi2[25], wf2[25], wg2[25];
#pragma unroll
  for (int c = 0; c < 25; ++c) {
    wi2[c] = __builtin_bit_cast(half2v, pw[((d * 3 + 0) * 25 + c) * 50 + j]);
    wf2[c] = __builtin_bit_cast(half2v, pw[((d * 3 + 1) * 25 + c) * 50 + j]);
    wg2[c] = __builtin_bit_cast(half2v, pw[((d * 3 + 2) * 25 + c) * 50 + j]);
  }

  const float* Xd = Xg + d * NS * 3 * NH;

  auto ldx = [&](int t) -> X3 {
    const int tt = d ? (NS - 1 - t) : t;
    X3 r;
    r.i = Xd[tt * 150 + j];
    r.f = Xd[tt * 150 + 50 + j];
    r.g = Xd[tt * 150 + 100 + j];
    return r;
  };

  float hj = 0.f, hs = 0.f;

  auto dostep = [&](X3 x) {
    float ai0 = x.i, af0 = x.f, ag0 = x.g;
    float ai1 = 0.f, af1 = 0.f, ag1 = 0.f;
    const float hpart = __builtin_bit_cast(float,
        __builtin_amdgcn_ds_swizzle(__builtin_bit_cast(int, hj), 0x041F));
    const half2v hpk = __builtin_amdgcn_cvt_pkrtz(hj, hpart);
    const int packed = __builtin_bit_cast(int, hpk);
#pragma unroll
    for (int c = 0; c < 25; ++c) {
      const half2v hk2 = __builtin_bit_cast(half2v,
          __builtin_amdgcn_readlane(packed, 2 * c));
      if (c & 1) {
        ai1 = fdot2(wi2[c], hk2, ai1);
        af1 = fdot2(wf2[c], hk2, af1);
        ag1 = fdot2(wg2[c], hk2, ag1);
      } else {
        ai0 = fdot2(wi2[c], hk2, ai0);
        af0 = fdot2(wf2[c], hk2, af0);
        ag0 = fdot2(wg2[c], hk2, ag0);
      }
    }
    const float it = fast_sigmoid(ai0 + ai1);
    const float ft = fast_sigmoid(af0 + af1);
    const float gt = fast_tanh(ag0 + ag1);
    hj = fast_tanh(it * gt + ft * hj);
    hs += hj;
  };

  // Depth-4 rolling prefetch: named slots, statically indexed.
  X3 p0 = ldx(0), p1 = ldx(1), p2 = ldx(2), p3 = ldx(3);

#pragma unroll 1
  for (int k = 0; k < NS / 4; ++k) {
    const int n = 4 * k;
    const int q0 = (n + 4 < NS) ? n + 4 : NS - 1;
    const int q1 = (n + 5 < NS) ? n + 5 : NS - 1;
    const int q2 = (n + 6 < NS) ? n + 6 : NS - 1;
    const int q3 = (n + 7 < NS) ? n + 7 : NS - 1;
    X3 c0 = p0; p0 = ldx(q0); dostep(c0);
    X3 c1 = p1; p1 = ldx(q1); dostep(c1);
    X3 c2 = p2; p2 = ldx(q2); dostep(c2);
    X3 c3 = p3; p3 = ldx(q3); dostep(c3);
  }

  if (lane < NH) gsum_sh[d * NH + lane] = hs * (1.f / 64.f);
  __syncthreads();

  // Epilogue (wave 0): logits + softmax
  if (d == 0) {
    float lg = 0.f;
    if (lane < NO) {
      float acc = bout[lane];
      for (int k = 0; k < 2 * NH; ++k) acc += Wout[lane * 2 * NH + k] * gsum_sh[k];
      lg = acc;
    }
    const float l0 = __shfl(lg, 0), l1 = __shfl(lg, 1), l2 = __shfl(lg, 2),
                l3 = __shfl(lg, 3), l4 = __shfl(lg, 4);
    if (lane == 0) {
      const float m = fmaxf(fmaxf(fmaxf(l0, l1), fmaxf(l2, l3)), l4);
      const float e0 = __expf(l0 - m), e1 = __expf(l1 - m), e2 = __expf(l2 - m),
                  e3 = __expf(l3 - m), e4 = __expf(l4 - m);
      const float se = e0 + e1 + e2 + e3 + e4;
      out[0] = e0 / se; out[1] = e1 / se; out[2] = e2 / se;
      out[3] = e3 / se; out[4] = e4 / se;
    }
  }
}

extern "C" void kernel_launch(void* const* d_in, const int* in_sizes, int n_in,
                              void* d_out, int out_size, void* d_ws, size_t ws_size,
                              hipStream_t stream) {
  const int*   doc   = (const int*)  d_in[0];
  const float* emb   = (const float*)d_in[1];
  const float* Wword = (const float*)d_in[2];
  const float* bword = (const float*)d_in[3];
  const float* w1    = (const float*)d_in[4];
  const float* b1    = (const float*)d_in[5];
  const float* w2    = (const float*)d_in[6];
  const float* b2    = (const float*)d_in[7];
  const float* w3    = (const float*)d_in[8];
  const float* b3    = (const float*)d_in[9];
  const float* Wfi   = (const float*)d_in[10];
  const float* bfi   = (const float*)d_in[11];
  const float* Wff   = (const float*)d_in[12];
  const float* bff   = (const float*)d_in[13];
  const float* Wfg   = (const float*)d_in[14];
  const float* bfg   = (const float*)d_in[15];
  const float* Wbi   = (const float*)d_in[16];
  const float* bbi   = (const float*)d_in[17];
  const float* Wbf   = (const float*)d_in[18];
  const float* bbf   = (const float*)d_in[19];
  const float* Wbg   = (const float*)d_in[20];
  const float* bbg   = (const float*)d_in[21];
  const float* Wout  = (const float*)d_in[22];
  const float* bout  = (const float*)d_in[23];

  float* Xg = (float*)d_ws + 64;                                  // 19200 floats
  unsigned int* pw = (unsigned int*)((float*)d_ws + 64 + 19200);  // 7500 u32

  k_reps<<<dim3(NS + 1), dim3(512), 0, stream>>>(
      doc, emb, Wword, bword, w1, b1, w2, b2, w3, b3,
      Wfi, bfi, Wff, bff, Wfg, bfg, Wbi, bbi, Wbf, bbf, Wbg, bbg,
      Xg, pw);

  k_scan<<<dim3(1), dim3(128), 0, stream>>>(
      Xg, pw, Wout, bout, (float*)d_out);
}